// Round 1
// baseline (197.835 us; speedup 1.0000x reference)
//
#include <hip/hip_runtime.h>
#include <math.h>

// Problem constants (from reference): N_ROWS=1048576, D=128, N_SEG=2048.
// Kernel is written generically against in_sizes anyway.

__global__ void zero_out_kernel(float* out) {
    out[0] = 0.0f;
}

__global__ __launch_bounds__(256) void euclid_loss_kernel(
    const float* __restrict__ remap,
    const float* __restrict__ emb,
    const int*   __restrict__ num_list,
    float*       __restrict__ out,
    int n_seg)
{
    const int seg  = blockIdx.x;
    const int tid  = threadIdx.x;
    const int wid  = tid >> 6;     // wave id 0..3
    const int lane = tid & 63;     // lane in wave
    const int sub  = lane >> 5;    // half-wave: 0 or 1 (row selector)
    const int l32  = lane & 31;    // lane within 32-group (covers one 128-f32 row via float4)

    __shared__ int   s_red[4];
    __shared__ int   s_start, s_len;
    __shared__ float s_acc[4];

    // ---- Phase A: segment offset = prefix sum of num_list[0..seg) ----
    int partial = 0;
    for (int i = tid; i < seg; i += 256) partial += num_list[i];
    #pragma unroll
    for (int off = 32; off >= 1; off >>= 1) partial += __shfl_down(partial, off, 64);
    if (lane == 0) s_red[wid] = partial;
    __syncthreads();
    if (tid == 0) {
        s_start = s_red[0] + s_red[1] + s_red[2] + s_red[3];
        s_len   = num_list[seg];
    }
    __syncthreads();
    const int seg_start = s_start;
    const int seg_len   = s_len;

    // ---- Phase B: per-row L2 distance, each wave does 2 rows / iter ----
    // 4 waves x 2 rows = 8 rows per block iteration; rows contiguous -> coalesced.
    float acc = 0.0f;
    for (int r = wid * 2 + sub; r < seg_len; r += 8) {
        const long long row = (long long)(seg_start + r);
        const float4 va = *((const float4*)(remap + row * 128) + l32);
        const float4 vb = *((const float4*)(emb   + row * 128) + l32);
        const float dx = va.x - vb.x;
        const float dy = va.y - vb.y;
        const float dz = va.z - vb.z;
        const float dw = va.w - vb.w;
        float s = dx * dx + dy * dy + dz * dz + dw * dw;
        // reduce across the 32-lane group holding this row
        s += __shfl_xor(s, 1, 64);
        s += __shfl_xor(s, 2, 64);
        s += __shfl_xor(s, 4, 64);
        s += __shfl_xor(s, 8, 64);
        s += __shfl_xor(s, 16, 64);
        if (l32 == 0) acc += sqrtf(s);
    }

    // ---- Phase C: block reduction + one atomic per segment ----
    #pragma unroll
    for (int off = 32; off >= 1; off >>= 1) acc += __shfl_down(acc, off, 64);
    if (lane == 0) s_acc[wid] = acc;
    __syncthreads();
    if (tid == 0) {
        const float total = s_acc[0] + s_acc[1] + s_acc[2] + s_acc[3];
        atomicAdd(out, total / (float)seg_len);
    }
}

extern "C" void kernel_launch(void* const* d_in, const int* in_sizes, int n_in,
                              void* d_out, int out_size, void* d_ws, size_t ws_size,
                              hipStream_t stream) {
    const float* remap    = (const float*)d_in[0];
    const float* emb      = (const float*)d_in[1];
    const int*   num_list = (const int*)d_in[2];
    float*       out      = (float*)d_out;

    const int n_seg = in_sizes[2];

    zero_out_kernel<<<1, 1, 0, stream>>>(out);
    euclid_loss_kernel<<<n_seg, 256, 0, stream>>>(remap, emb, num_list, out, n_seg);
}

// Round 2
// 176.873 us; speedup vs baseline: 1.1185x; 1.1185x over previous
//
#include <hip/hip_runtime.h>
#include <math.h>

typedef float v4f __attribute__((ext_vector_type(4)));

// Prep: zero the output scalar and exclusive-scan num_list -> seg_start (d_ws).
// One block, 256 threads; n_seg=2048 -> 8 elements/thread chunk scan.
__global__ __launch_bounds__(256) void prep_kernel(const int* __restrict__ num_list,
                                                   int n_seg,
                                                   float* __restrict__ out,
                                                   int* __restrict__ seg_start) {
    __shared__ int s_sum[256];
    const int tid = threadIdx.x;
    const int C  = (n_seg + 255) >> 8;          // chunk size per thread
    const int lo = tid * C;
    const int hi = (lo + C < n_seg) ? (lo + C) : n_seg;

    int sum = 0;
    for (int i = lo; i < hi; ++i) sum += num_list[i];
    s_sum[tid] = sum;
    __syncthreads();

    // Hillis-Steele inclusive scan over the 256 chunk sums
    for (int off = 1; off < 256; off <<= 1) {
        int v   = s_sum[tid];
        int add = (tid >= off) ? s_sum[tid - off] : 0;
        __syncthreads();
        s_sum[tid] = v + add;
        __syncthreads();
    }

    int excl = (tid == 0) ? 0 : s_sum[tid - 1];
    for (int i = lo; i < hi; ++i) {
        seg_start[i] = excl;
        excl += num_list[i];
    }
    if (tid == 0) out[0] = 0.0f;
}

__global__ __launch_bounds__(256) void euclid_loss_kernel(
    const float* __restrict__ remap,
    const float* __restrict__ emb,
    const int*   __restrict__ num_list,
    const int*   __restrict__ seg_start_arr,
    float*       __restrict__ out)
{
    const int seg  = blockIdx.x;
    const int tid  = threadIdx.x;
    const int wid  = tid >> 6;     // wave id 0..3
    const int lane = tid & 63;
    const int sub  = lane >> 5;    // half-wave row selector
    const int l32  = lane & 31;    // lane within 32-group (one 128-f32 row via float4)

    const int seg_start = seg_start_arr[seg];
    const int seg_len   = num_list[seg];

    const v4f* __restrict__ pa = (const v4f*)remap;
    const v4f* __restrict__ pb = (const v4f*)emb;

    float acc = 0.0f;
    int r = wid * 2 + sub;

    // Unrolled: each wave handles rows {r, r+8} per iter -> 4 nt-loads in flight.
    for (; r + 8 < seg_len; r += 16) {
        const long long row0 = (long long)(seg_start + r);
        const long long row1 = row0 + 8;
        const v4f a0 = __builtin_nontemporal_load(pa + row0 * 32 + l32);
        const v4f b0 = __builtin_nontemporal_load(pb + row0 * 32 + l32);
        const v4f a1 = __builtin_nontemporal_load(pa + row1 * 32 + l32);
        const v4f b1 = __builtin_nontemporal_load(pb + row1 * 32 + l32);
        const v4f d0 = a0 - b0;
        const v4f d1 = a1 - b1;
        float s0 = d0[0]*d0[0] + d0[1]*d0[1] + d0[2]*d0[2] + d0[3]*d0[3];
        float s1 = d1[0]*d1[0] + d1[1]*d1[1] + d1[2]*d1[2] + d1[3]*d1[3];
        #pragma unroll
        for (int m = 1; m <= 16; m <<= 1) s0 += __shfl_xor(s0, m, 64);
        #pragma unroll
        for (int m = 1; m <= 16; m <<= 1) s1 += __shfl_xor(s1, m, 64);
        if (l32 == 0) acc += sqrtf(s0) + sqrtf(s1);
    }
    // Tail (single row per iter)
    for (; r < seg_len; r += 8) {
        const long long row = (long long)(seg_start + r);
        const v4f a = __builtin_nontemporal_load(pa + row * 32 + l32);
        const v4f b = __builtin_nontemporal_load(pb + row * 32 + l32);
        const v4f d = a - b;
        float s = d[0]*d[0] + d[1]*d[1] + d[2]*d[2] + d[3]*d[3];
        #pragma unroll
        for (int m = 1; m <= 16; m <<= 1) s += __shfl_xor(s, m, 64);
        if (l32 == 0) acc += sqrtf(s);
    }

    // Block reduction + one atomic per segment
    #pragma unroll
    for (int off = 32; off >= 1; off >>= 1) acc += __shfl_down(acc, off, 64);
    __shared__ float s_acc[4];
    if (lane == 0) s_acc[wid] = acc;
    __syncthreads();
    if (tid == 0) {
        atomicAdd(out, (s_acc[0] + s_acc[1] + s_acc[2] + s_acc[3]) / (float)seg_len);
    }
}

extern "C" void kernel_launch(void* const* d_in, const int* in_sizes, int n_in,
                              void* d_out, int out_size, void* d_ws, size_t ws_size,
                              hipStream_t stream) {
    const float* remap    = (const float*)d_in[0];
    const float* emb      = (const float*)d_in[1];
    const int*   num_list = (const int*)d_in[2];
    float*       out      = (float*)d_out;
    int*         seg_start = (int*)d_ws;   // n_seg ints of scratch

    const int n_seg = in_sizes[2];

    prep_kernel<<<1, 256, 0, stream>>>(num_list, n_seg, out, seg_start);
    euclid_loss_kernel<<<n_seg, 256, 0, stream>>>(remap, emb, num_list, seg_start, out);
}

// Round 3
// 166.520 us; speedup vs baseline: 1.1881x; 1.0622x over previous
//
#include <hip/hip_runtime.h>
#include <math.h>

typedef float v4f __attribute__((ext_vector_type(4)));

// Main: one block per segment. Computes its own segment offset via an
// in-block reduction over num_list[0..seg) (L2-resident, overlapped across
// all co-resident blocks), streams the two embeddings with nontemporal
// float4 loads, and stores its partial (sum_sqrt / seg_len) to ws[seg].
// No atomics, no pre-zeroed state -> deterministic under graph replay.
__global__ __launch_bounds__(256) void euclid_loss_kernel(
    const float* __restrict__ remap,
    const float* __restrict__ emb,
    const int*   __restrict__ num_list,
    float*       __restrict__ ws)
{
    const int seg  = blockIdx.x;
    const int tid  = threadIdx.x;
    const int wid  = tid >> 6;     // wave id 0..3
    const int lane = tid & 63;
    const int sub  = lane >> 5;    // half-wave row selector (0/1)
    const int l32  = lane & 31;    // lane within 32-group: one 128-f32 row via float4

    __shared__ int   s_red[4];
    __shared__ int   s_start;
    __shared__ float s_acc[4];

    // ---- segment offset = sum of num_list[0..seg) ----
    int partial = 0;
    for (int i = tid; i < seg; i += 256) partial += num_list[i];
    #pragma unroll
    for (int off = 32; off >= 1; off >>= 1) partial += __shfl_down(partial, off, 64);
    if (lane == 0) s_red[wid] = partial;
    __syncthreads();
    if (tid == 0) s_start = s_red[0] + s_red[1] + s_red[2] + s_red[3];
    __syncthreads();
    const int seg_start = s_start;
    const int seg_len   = num_list[seg];

    const v4f* __restrict__ pa = (const v4f*)remap;
    const v4f* __restrict__ pb = (const v4f*)emb;

    float acc = 0.0f;
    int r = wid * 2 + sub;

    // 4 rows per wave-iter -> 8 nontemporal dwordx4 loads in flight.
    for (; r + 24 < seg_len; r += 32) {
        const long long row0 = (long long)(seg_start + r);
        const v4f a0 = __builtin_nontemporal_load(pa + (row0     ) * 32 + l32);
        const v4f b0 = __builtin_nontemporal_load(pb + (row0     ) * 32 + l32);
        const v4f a1 = __builtin_nontemporal_load(pa + (row0 +  8) * 32 + l32);
        const v4f b1 = __builtin_nontemporal_load(pb + (row0 +  8) * 32 + l32);
        const v4f a2 = __builtin_nontemporal_load(pa + (row0 + 16) * 32 + l32);
        const v4f b2 = __builtin_nontemporal_load(pb + (row0 + 16) * 32 + l32);
        const v4f a3 = __builtin_nontemporal_load(pa + (row0 + 24) * 32 + l32);
        const v4f b3 = __builtin_nontemporal_load(pb + (row0 + 24) * 32 + l32);
        const v4f d0 = a0 - b0;
        const v4f d1 = a1 - b1;
        const v4f d2 = a2 - b2;
        const v4f d3 = a3 - b3;
        float s0 = d0[0]*d0[0] + d0[1]*d0[1] + d0[2]*d0[2] + d0[3]*d0[3];
        float s1 = d1[0]*d1[0] + d1[1]*d1[1] + d1[2]*d1[2] + d1[3]*d1[3];
        float s2 = d2[0]*d2[0] + d2[1]*d2[1] + d2[2]*d2[2] + d2[3]*d2[3];
        float s3 = d3[0]*d3[0] + d3[1]*d3[1] + d3[2]*d3[2] + d3[3]*d3[3];
        #pragma unroll
        for (int m = 1; m <= 16; m <<= 1) {
            s0 += __shfl_xor(s0, m, 64);
            s1 += __shfl_xor(s1, m, 64);
            s2 += __shfl_xor(s2, m, 64);
            s3 += __shfl_xor(s3, m, 64);
        }
        if (l32 == 0) acc += sqrtf(s0) + sqrtf(s1) + sqrtf(s2) + sqrtf(s3);
    }
    // Tail (single row per iter)
    for (; r < seg_len; r += 8) {
        const long long row = (long long)(seg_start + r);
        const v4f a = __builtin_nontemporal_load(pa + row * 32 + l32);
        const v4f b = __builtin_nontemporal_load(pb + row * 32 + l32);
        const v4f d = a - b;
        float s = d[0]*d[0] + d[1]*d[1] + d[2]*d[2] + d[3]*d[3];
        #pragma unroll
        for (int m = 1; m <= 16; m <<= 1) s += __shfl_xor(s, m, 64);
        if (l32 == 0) acc += sqrtf(s);
    }

    // Block reduction; plain store of the per-segment partial (no atomic).
    #pragma unroll
    for (int off = 32; off >= 1; off >>= 1) acc += __shfl_down(acc, off, 64);
    if (lane == 0) s_acc[wid] = acc;
    __syncthreads();
    if (tid == 0) {
        ws[seg] = (s_acc[0] + s_acc[1] + s_acc[2] + s_acc[3]) / (float)seg_len;
    }
}

// Final: one block sums the n_seg partials (L2-hot) into out[0].
__global__ __launch_bounds__(256) void final_reduce_kernel(
    const float* __restrict__ ws, int n_seg, float* __restrict__ out)
{
    const int tid  = threadIdx.x;
    const int wid  = tid >> 6;
    const int lane = tid & 63;
    __shared__ float s_acc[4];

    float acc = 0.0f;
    for (int i = tid; i < n_seg; i += 256) acc += ws[i];
    #pragma unroll
    for (int off = 32; off >= 1; off >>= 1) acc += __shfl_down(acc, off, 64);
    if (lane == 0) s_acc[wid] = acc;
    __syncthreads();
    if (tid == 0) out[0] = s_acc[0] + s_acc[1] + s_acc[2] + s_acc[3];
}

extern "C" void kernel_launch(void* const* d_in, const int* in_sizes, int n_in,
                              void* d_out, int out_size, void* d_ws, size_t ws_size,
                              hipStream_t stream) {
    const float* remap    = (const float*)d_in[0];
    const float* emb      = (const float*)d_in[1];
    const int*   num_list = (const int*)d_in[2];
    float*       out      = (float*)d_out;
    float*       ws       = (float*)d_ws;   // n_seg floats of scratch

    const int n_seg = in_sizes[2];

    euclid_loss_kernel<<<n_seg, 256, 0, stream>>>(remap, emb, num_list, ws);
    final_reduce_kernel<<<1, 256, 0, stream>>>(ws, n_seg, out);
}